// Round 12
// baseline (7519.381 us; speedup 1.0000x reference)
//
#include <hip/hip_runtime.h>

#define BB 8
#define TT 2000
#define DD 64
#define NN 2000
#define NWG 125
#define COLS 16
#define THREADS 512
#define SROW 2048          // wS LDS row stride (bf16)
#define XST 68

// LDS: wS 16*2048*2=65536, winS 16*68*4=4352, red 8*8*16*4=4096
#define LDS_BYTES (65536 + 4352 + 4096)

typedef __bf16 bf16x8 __attribute__((ext_vector_type(8)));
typedef float f32x4 __attribute__((ext_vector_type(4)));

__device__ __forceinline__ float fast_tanh(float v) {
    float e = __expf(2.0f * v);
    return 1.0f - 2.0f / (e + 1.0f);
}

// ---- uncached (coherence-point) accessors: sc0 sc1 = bypass L1/L2, served by IC ----
__device__ __forceinline__ uint4 ld_uc4(const void* p) {
    uint4 v;
    asm volatile("global_load_dwordx4 %0, %1, off sc0 sc1" : "=v"(v) : "v"(p) : "memory");
    return v;
}
__device__ __forceinline__ void st_uc_u16(void* p, unsigned v) {
    asm volatile("global_store_short %0, %1, off sc0 sc1" :: "v"(p), "v"(v) : "memory");
}
__device__ __forceinline__ void st_uc_u32(void* p, unsigned v) {
    asm volatile("global_store_dword %0, %1, off sc0 sc1" :: "v"(p), "v"(v) : "memory");
}

// single-lane (exec=1) 2-deep pipelined poll until *p >= tgt
__device__ __forceinline__ void poll_ge_pipelined(const unsigned* p, unsigned tgt) {
    unsigned a, b;
    asm volatile(
        "global_load_dword %0, %2, off sc0 sc1\n\t"
        "global_load_dword %1, %2, off sc0 sc1\n\t"
        "Lp_%=:\n\t"
        "s_waitcnt vmcnt(1)\n\t"
        "v_cmp_le_u32 vcc, %3, %0\n\t"
        "s_cbranch_vccnz Ld_%=\n\t"
        "global_load_dword %0, %2, off sc0 sc1\n\t"
        "s_waitcnt vmcnt(1)\n\t"
        "v_cmp_le_u32 vcc, %3, %1\n\t"
        "s_cbranch_vccnz Ld_%=\n\t"
        "global_load_dword %1, %2, off sc0 sc1\n\t"
        "s_branch Lp_%=\n\t"
        "Ld_%=:\n\t"
        "s_waitcnt vmcnt(0)\n\t"
        : "=&v"(a), "=&v"(b)
        : "v"(p), "v"(tgt)
        : "vcc", "memory");
}

// full-wave 2-deep pipelined sweep: wait until flags at p0[lane] and p1[lane]
// are all >= tgt across the wave
__device__ __forceinline__ void sweep_all_ge(const unsigned* p0, const unsigned* p1,
                                             unsigned tgt) {
    unsigned a, b, c, d;
    unsigned long long sm;
    asm volatile(
        "global_load_dword %0, %5, off sc0 sc1\n\t"
        "global_load_dword %1, %6, off sc0 sc1\n\t"
        "global_load_dword %2, %5, off sc0 sc1\n\t"
        "global_load_dword %3, %6, off sc0 sc1\n\t"
        "Ls_%=:\n\t"
        "s_waitcnt vmcnt(2)\n\t"
        "v_cmp_le_u32 vcc, %7, %0\n\t"
        "s_mov_b64 %4, vcc\n\t"
        "v_cmp_le_u32 vcc, %7, %1\n\t"
        "s_and_b64 %4, %4, vcc\n\t"
        "s_xor_b64 %4, %4, exec\n\t"
        "s_cbranch_scc0 Ld_%=\n\t"
        "global_load_dword %0, %5, off sc0 sc1\n\t"
        "global_load_dword %1, %6, off sc0 sc1\n\t"
        "s_waitcnt vmcnt(2)\n\t"
        "v_cmp_le_u32 vcc, %7, %2\n\t"
        "s_mov_b64 %4, vcc\n\t"
        "v_cmp_le_u32 vcc, %7, %3\n\t"
        "s_and_b64 %4, %4, vcc\n\t"
        "s_xor_b64 %4, %4, exec\n\t"
        "s_cbranch_scc0 Ld_%=\n\t"
        "global_load_dword %2, %5, off sc0 sc1\n\t"
        "global_load_dword %3, %6, off sc0 sc1\n\t"
        "s_branch Ls_%=\n\t"
        "Ld_%=:\n\t"
        "s_waitcnt vmcnt(0)\n\t"
        : "=&v"(a), "=&v"(b), "=&v"(c), "=&v"(d), "=&s"(sm)
        : "v"(p0), "v"(p1), "v"(tgt)
        : "vcc", "memory");
}

// State buffer sG: MFMA-A-fragment order (per gen, 32 KB); granule(kb,b) at
// 16B-index (kb>>2)*32 + (kb&3)*8 + b. Wave w step m reads contiguous 512 B
// region (w*8+m); lane l -> offset ((l>>4)*8 + (l&7))*16. Pad kb>=250 stays 0.

__global__ void __launch_bounds__(THREADS, 1)
esn_recur(const float* __restrict__ x, const float* __restrict__ Win,
          const float* __restrict__ Wres, char* __restrict__ sgB,
          float* __restrict__ H, unsigned* __restrict__ flags,
          unsigned* __restrict__ gen)
{
    extern __shared__ char smraw[];
    __bf16* wS   = (__bf16*)smraw;                 // [16][2048] swizzled: blk^(c&7)
    float*  winS = (float*)(wS + 16 * SROW);       // [16][68]
    float*  red  = winS + 16 * XST;                // [8 waves][8 rows][16 cols]

    const int tid  = threadIdx.x;
    const int wg   = blockIdx.x;
    const int col0 = wg * COLS;
    const int wave = tid >> 6;
    const int lane = tid & 63;

    for (int i = tid; i < LDS_BYTES / 4; i += THREADS) ((unsigned*)smraw)[i] = 0u;
    __syncthreads();

    // one-time: Wres slice transposed, bf16, XOR-swizzled 16B blocks
    {
        const int c = tid & 15, h = c & 7;
        for (int k = tid >> 4; k < NN; k += 32)
            wS[c * SROW + ((((k >> 3) ^ h) << 3) | (k & 7))] =
                (__bf16)Wres[(size_t)k * NN + col0 + c];
    }
    // one-time: Win slice (f32)
    for (int i = tid; i < COLS * DD; i += THREADS) {
        int c = i >> 6, d = i & 63;
        winS[c * XST + d] = Win[(size_t)d * NN + col0 + c];
    }
    __syncthreads();

    const int quad = lane >> 4;
    const int bcol = lane & 15;
    const int hb   = bcol & 7;
    const int fb = lane >> 4, fc = lane & 15;
    const int cg = col0 + fc;
    const int pReg = cg >> 5, pSub = (cg >> 3) & 3, pJ = (cg & 7) * 2;
    const size_t pOff0 = (((size_t)(pReg * 32 + pSub * 8 + fb    )) << 4) + pJ;
    const size_t pOff1 = (((size_t)(pReg * 32 + pSub * 8 + fb + 4)) << 4) + pJ;
    const size_t aLane = (size_t)((quad * 8 + (lane & 7)) << 4);
    const unsigned* f1 = flags + lane;
    const unsigned* f2 = flags + ((lane < 61) ? (64 + lane) : 0);
    const bool sweeper = (wg == 0) && (wave == 0);
    const unsigned* myGen = gen + wave * 16;       // 8 mirrors, 64 B apart

    // ---- hoist B fragments into registers for the whole kernel ----
    // laundered через scalar asm so the compiler cannot re-derive from LDS
    unsigned bw[8][4];
    {
        const __bf16* bBase = wS + bcol * SROW;
        const int blk0 = wave * 32 + quad;
        #pragma unroll
        for (int m = 0; m < 8; ++m) {
            uint4 v = *(const uint4*)(bBase + (((blk0 + m * 4) ^ hb) << 3));
            bw[m][0] = v.x; bw[m][1] = v.y; bw[m][2] = v.z; bw[m][3] = v.w;
            asm volatile("" : "+v"(bw[m][0]), "+v"(bw[m][1]),
                              "+v"(bw[m][2]), "+v"(bw[m][3]));
        }
    }

    for (int t = 0; t < TT; ++t) {
        // x@Win partials (producer wave only) — L2-cached x, off the signal path
        float xa0 = 0.f, xa1 = 0.f;
        if (wave == 1) {
            const float4* xr0 = (const float4*)(x + ((size_t)fb * TT + t) * DD);
            const float4* xr1 = (const float4*)(x + ((size_t)(fb + 4) * TT + t) * DD);
            const float4* wv  = (const float4*)(winS + fc * XST);
            #pragma unroll
            for (int d4 = 0; d4 < 16; ++d4) {
                float4 w = wv[d4];
                float4 u0 = xr0[d4], u1 = xr1[d4];
                xa0 = fmaf(u0.x, w.x, xa0); xa0 = fmaf(u0.y, w.y, xa0);
                xa0 = fmaf(u0.z, w.z, xa0); xa0 = fmaf(u0.w, w.w, xa0);
                xa1 = fmaf(u1.x, w.x, xa1); xa1 = fmaf(u1.y, w.y, xa1);
                xa1 = fmaf(u1.z, w.z, xa1); xa1 = fmaf(u1.w, w.w, xa1);
            }
        }

        f32x4 acc = {0.f, 0.f, 0.f, 0.f};
        if (t > 0) {
            // per-wave gating: sweeper aggregates flags -> 8 gen mirrors;
            // every other wave single-lane pipelined-polls ITS mirror, then
            // fires its A-load immediately (no block release barrier).
            const unsigned tgt = (unsigned)t;
            if (sweeper) {
                sweep_all_ge(f1, f2, tgt);
                if (lane < 8) st_uc_u32((void*)(gen + lane * 16), tgt);
            } else if (lane == 0) {
                poll_ge_pipelined(myGen, tgt);
            }

            // A-operand: 8 contiguous coalesced 512 B region loads -> MFMA frags
            const char* aB = sgB + (size_t)(t & 1) * 32768 + wave * 4096 + aLane;
            uint4 a0 = ld_uc4(aB);
            uint4 a1 = ld_uc4(aB + 512);
            uint4 a2 = ld_uc4(aB + 1024);
            uint4 a3 = ld_uc4(aB + 1536);
            uint4 a4 = ld_uc4(aB + 2048);
            uint4 a5 = ld_uc4(aB + 2560);
            uint4 a6 = ld_uc4(aB + 3072);
            uint4 a7 = ld_uc4(aB + 3584);
            asm volatile("s_waitcnt vmcnt(0)" ::: "memory");
            __builtin_amdgcn_sched_barrier(0);     // rule #18: pin MFMA below wait

            #define MSTEP(mm, areg) { \
                uint4 bu = make_uint4(bw[mm][0], bw[mm][1], bw[mm][2], bw[mm][3]); \
                acc = __builtin_amdgcn_mfma_f32_16x16x32_bf16( \
                    __builtin_bit_cast(bf16x8, areg), \
                    __builtin_bit_cast(bf16x8, bu), acc, 0, 0, 0); }
            MSTEP(0, a0) MSTEP(1, a1) MSTEP(2, a2) MSTEP(3, a3)
            MSTEP(4, a4) MSTEP(5, a5) MSTEP(6, a6) MSTEP(7, a7)
            #undef MSTEP
        }
        if (lane < 32) {
            const int r0 = (lane >> 4) * 4;
            #pragma unroll
            for (int i = 0; i < 4; ++i)
                red[(wave * 8 + r0 + i) * 16 + bcol] = acc[i];
        }
        __syncthreads();

        // finish (wave 1 only): 2 outputs/thread; drain own stores, then ONE
        // plain uncached flag store.
        if (wave == 1) {
            float a0s = xa0, a1s = xa1;
            #pragma unroll
            for (int w = 0; w < 8; ++w) {
                a0s += red[(w * 8 + fb    ) * 16 + fc];
                a1s += red[(w * 8 + fb + 4) * 16 + fc];
            }
            float s0 = fast_tanh(a0s);
            float s1 = fast_tanh(a1s);
            if (t < TT - 1) {
                __bf16 b0 = (__bf16)s0, b1 = (__bf16)s1;
                unsigned short u0, u1;
                __builtin_memcpy(&u0, &b0, 2);
                __builtin_memcpy(&u1, &b1, 2);
                char* dstG = sgB + (size_t)((t + 1) & 1) * 32768;
                st_uc_u16(dstG + pOff0, (unsigned)u0);
                st_uc_u16(dstG + pOff1, (unsigned)u1);
                asm volatile("s_waitcnt vmcnt(0)" ::: "memory");  // state at IC
                if (lane == 0) st_uc_u32(flags + wg, (unsigned)(t + 1));
            }
            float h0 = (fc & 1) ? s0 : s0 * s0;   // even global col -> square
            float h1 = (fc & 1) ? s1 : s1 * s1;
            H[((size_t)t * BB + fb    ) * NN + col0 + fc] = h0;   // off signal path
            H[((size_t)t * BB + fb + 4) * NN + col0 + fc] = h1;
        }
    }
}

// out[b,t,:] = H[t,b,:] @ Wout  (augmentation already applied in H)
__global__ void __launch_bounds__(256, 1)
esn_out(const float* __restrict__ H, const float* __restrict__ Wout,
        float* __restrict__ out)
{
    __shared__ float Hs[64 * 84];
    __shared__ float Ws[80 * 64];
    const int tid = threadIdx.x;
    const int r0  = blockIdx.x * 64;      // global row = t*8 + b
    const int tr  = tid >> 4;             // 0..15
    const int tc  = tid & 15;             // 0..15
    float acc[4][4] = {{0.f}};

    for (int k0 = 0; k0 < NN; k0 += 80) {
        __syncthreads();
        #pragma unroll
        for (int j = 0; j < 5; ++j) {
            int idx = j * 256 + tid;               // 0..1279
            int r = idx / 20, q = idx % 20;
            *(float4*)&Hs[r * 84 + q * 4] =
                *(const float4*)&H[(size_t)(r0 + r) * NN + k0 + q * 4];
        }
        #pragma unroll
        for (int j = 0; j < 5; ++j) {
            int idx = j * 256 + tid;
            int kk = idx >> 4, c4 = idx & 15;
            *(float4*)&Ws[kk * 64 + c4 * 4] =
                *(const float4*)&Wout[(size_t)(k0 + kk) * DD + c4 * 4];
        }
        __syncthreads();
        for (int kk = 0; kk < 80; ++kk) {
            float4 wv = *(const float4*)&Ws[kk * 64 + tc * 4];
            #pragma unroll
            for (int i = 0; i < 4; ++i) {
                float hv = Hs[(tr + 16 * i) * 84 + kk];
                acc[i][0] = fmaf(hv, wv.x, acc[i][0]);
                acc[i][1] = fmaf(hv, wv.y, acc[i][1]);
                acc[i][2] = fmaf(hv, wv.z, acc[i][2]);
                acc[i][3] = fmaf(hv, wv.w, acc[i][3]);
            }
        }
    }
    #pragma unroll
    for (int i = 0; i < 4; ++i) {
        int rg = r0 + tr + 16 * i;
        int t = rg >> 3, b = rg & 7;
        *(float4*)&out[((size_t)b * TT + t) * DD + tc * 4] =
            make_float4(acc[i][0], acc[i][1], acc[i][2], acc[i][3]);
    }
}

extern "C" void kernel_launch(void* const* d_in, const int* in_sizes, int n_in,
                              void* d_out, int out_size, void* d_ws, size_t ws_size,
                              hipStream_t stream)
{
    const float* x    = (const float*)d_in[0];
    const float* Win  = (const float*)d_in[1];
    const float* Wres = (const float*)d_in[2];
    const float* Wout = (const float*)d_in[3];
    float* out = (float*)d_out;

    char* ws = (char*)d_ws;
    unsigned* flags = (unsigned*)ws;                 // 125 dwords
    unsigned* gen   = (unsigned*)(ws + 2048);        // 8 mirrors, 64 B apart
    char* sG  = ws + 4096;                           // 2 gens * 32 KB fragment-order state
    float* H  = (float*)(ws + 4096 + 65536);         // 2000*8*2000 f32 = 128 MB

    (void)hipMemsetAsync(d_ws, 0, 4096 + 65536, stream);

    (void)hipFuncSetAttribute((const void*)esn_recur,
                              hipFuncAttributeMaxDynamicSharedMemorySize, LDS_BYTES);
    esn_recur<<<NWG, THREADS, LDS_BYTES, stream>>>(x, Win, Wres, sG, H, flags, gen);
    esn_out<<<250, 256, 0, stream>>>(H, Wout, out);
}

// Round 13
// 5999.213 us; speedup vs baseline: 1.2534x; 1.2534x over previous
//
#include <hip/hip_runtime.h>

#define BB 8
#define TT 2000
#define DD 64
#define NN 2000
#define NWG 125
#define COLS 16
#define THREADS 512
#define SROW 2048          // wS LDS row stride (bf16)
#define XST 68

// LDS: wS 16*2048*2=65536, winS 16*68*4=4352, red 8*8*16*4=4096
#define LDS_BYTES (65536 + 4352 + 4096)

typedef __bf16 bf16x8 __attribute__((ext_vector_type(8)));
typedef float f32x4 __attribute__((ext_vector_type(4)));

__device__ __forceinline__ float fast_tanh(float v) {
    float e = __expf(2.0f * v);
    return 1.0f - 2.0f / (e + 1.0f);
}

// ---- uncached (coherence-point) accessors: sc0 sc1 = bypass L1/L2, served by IC ----
__device__ __forceinline__ uint4 ld_uc4(const void* p) {
    uint4 v;
    asm volatile("global_load_dwordx4 %0, %1, off sc0 sc1" : "=v"(v) : "v"(p) : "memory");
    return v;
}
__device__ __forceinline__ void st_uc_u16(void* p, unsigned v) {
    asm volatile("global_store_short %0, %1, off sc0 sc1" :: "v"(p), "v"(v) : "memory");
}
__device__ __forceinline__ void st_uc_u32(void* p, unsigned v) {
    asm volatile("global_store_dword %0, %1, off sc0 sc1" :: "v"(p), "v"(v) : "memory");
}

// single-lane (exec=1) 2-deep pipelined poll until *p >= tgt
__device__ __forceinline__ void poll_ge_pipelined(const unsigned* p, unsigned tgt) {
    unsigned a, b;
    asm volatile(
        "global_load_dword %0, %2, off sc0 sc1\n\t"
        "global_load_dword %1, %2, off sc0 sc1\n\t"
        "Lp_%=:\n\t"
        "s_waitcnt vmcnt(1)\n\t"
        "v_cmp_le_u32 vcc, %3, %0\n\t"
        "s_cbranch_vccnz Ld_%=\n\t"
        "global_load_dword %0, %2, off sc0 sc1\n\t"
        "s_waitcnt vmcnt(1)\n\t"
        "v_cmp_le_u32 vcc, %3, %1\n\t"
        "s_cbranch_vccnz Ld_%=\n\t"
        "global_load_dword %1, %2, off sc0 sc1\n\t"
        "s_branch Lp_%=\n\t"
        "Ld_%=:\n\t"
        "s_waitcnt vmcnt(0)\n\t"
        : "=&v"(a), "=&v"(b)
        : "v"(p), "v"(tgt)
        : "vcc", "memory");
}

// full-wave 2-deep pipelined sweep: wait until flags at p0[lane] and p1[lane]
// are all >= tgt across the wave
__device__ __forceinline__ void sweep_all_ge(const unsigned* p0, const unsigned* p1,
                                             unsigned tgt) {
    unsigned a, b, c, d;
    unsigned long long sm;
    asm volatile(
        "global_load_dword %0, %5, off sc0 sc1\n\t"
        "global_load_dword %1, %6, off sc0 sc1\n\t"
        "global_load_dword %2, %5, off sc0 sc1\n\t"
        "global_load_dword %3, %6, off sc0 sc1\n\t"
        "Ls_%=:\n\t"
        "s_waitcnt vmcnt(2)\n\t"
        "v_cmp_le_u32 vcc, %7, %0\n\t"
        "s_mov_b64 %4, vcc\n\t"
        "v_cmp_le_u32 vcc, %7, %1\n\t"
        "s_and_b64 %4, %4, vcc\n\t"
        "s_xor_b64 %4, %4, exec\n\t"
        "s_cbranch_scc0 Ld_%=\n\t"
        "global_load_dword %0, %5, off sc0 sc1\n\t"
        "global_load_dword %1, %6, off sc0 sc1\n\t"
        "s_waitcnt vmcnt(2)\n\t"
        "v_cmp_le_u32 vcc, %7, %2\n\t"
        "s_mov_b64 %4, vcc\n\t"
        "v_cmp_le_u32 vcc, %7, %3\n\t"
        "s_and_b64 %4, %4, vcc\n\t"
        "s_xor_b64 %4, %4, exec\n\t"
        "s_cbranch_scc0 Ld_%=\n\t"
        "global_load_dword %2, %5, off sc0 sc1\n\t"
        "global_load_dword %3, %6, off sc0 sc1\n\t"
        "s_branch Ls_%=\n\t"
        "Ld_%=:\n\t"
        "s_waitcnt vmcnt(0)\n\t"
        : "=&v"(a), "=&v"(b), "=&v"(c), "=&v"(d), "=&s"(sm)
        : "v"(p0), "v"(p1), "v"(tgt)
        : "vcc", "memory");
}

// State buffer sG: MFMA-A-fragment order (per gen, 32 KB); granule(kb,b) at
// 16B-index (kb>>2)*32 + (kb&3)*8 + b. Wave w step m reads contiguous 512 B
// region (w*8+m); lane l -> offset ((l>>4)*8 + (l&7))*16. Pad kb>=250 stays 0.

__global__ void __launch_bounds__(THREADS, 1)
esn_recur(const float* __restrict__ x, const float* __restrict__ Win,
          const float* __restrict__ Wres, char* __restrict__ sgB,
          float* __restrict__ H, unsigned* __restrict__ flags,
          unsigned* __restrict__ gen)
{
    extern __shared__ char smraw[];
    __bf16* wS   = (__bf16*)smraw;                 // [16][2048] swizzled: blk^(c&7)
    float*  winS = (float*)(wS + 16 * SROW);       // [16][68]
    float*  red  = winS + 16 * XST;                // [8 waves][8 rows][16 cols]

    const int tid  = threadIdx.x;
    const int wg   = blockIdx.x;
    const int col0 = wg * COLS;
    const int wave = tid >> 6;
    const int lane = tid & 63;

    for (int i = tid; i < LDS_BYTES / 4; i += THREADS) ((unsigned*)smraw)[i] = 0u;
    __syncthreads();

    // one-time: Wres slice transposed, bf16, XOR-swizzled 16B blocks
    {
        const int c = tid & 15, h = c & 7;
        for (int k = tid >> 4; k < NN; k += 32)
            wS[c * SROW + ((((k >> 3) ^ h) << 3) | (k & 7))] =
                (__bf16)Wres[(size_t)k * NN + col0 + c];
    }
    // one-time: Win slice (f32)
    for (int i = tid; i < COLS * DD; i += THREADS) {
        int c = i >> 6, d = i & 63;
        winS[c * XST + d] = Win[(size_t)d * NN + col0 + c];
    }
    __syncthreads();

    const int quad = lane >> 4;
    const int bcol = lane & 15;
    const int hb   = bcol & 7;
    const int fb = lane >> 4, fc = lane & 15;
    const int cg = col0 + fc;
    const int pReg = cg >> 5, pSub = (cg >> 3) & 3, pJ = (cg & 7) * 2;
    const size_t pOff0 = (((size_t)(pReg * 32 + pSub * 8 + fb    )) << 4) + pJ;
    const size_t pOff1 = (((size_t)(pReg * 32 + pSub * 8 + fb + 4)) << 4) + pJ;
    const size_t aLane = (size_t)((quad * 8 + (lane & 7)) << 4);
    const unsigned* f1 = flags + lane;
    const unsigned* f2 = flags + ((lane < 61) ? (64 + lane) : 0);

    // ---- hoist B fragments into registers for the whole kernel ----
    unsigned bw[8][4];
    {
        const __bf16* bBase = wS + bcol * SROW;
        const int blk0 = wave * 32 + quad;
        #pragma unroll
        for (int m = 0; m < 8; ++m) {
            uint4 v = *(const uint4*)(bBase + (((blk0 + m * 4) ^ hb) << 3));
            bw[m][0] = v.x; bw[m][1] = v.y; bw[m][2] = v.z; bw[m][3] = v.w;
            asm volatile("" : "+v"(bw[m][0]), "+v"(bw[m][1]),
                              "+v"(bw[m][2]), "+v"(bw[m][3]));
        }
    }

    for (int t = 0; t < TT; ++t) {
        // x@Win partials (producer wave only) — L2-cached x, off the signal path
        float xa0 = 0.f, xa1 = 0.f;
        if (wave == 1) {
            const float4* xr0 = (const float4*)(x + ((size_t)fb * TT + t) * DD);
            const float4* xr1 = (const float4*)(x + ((size_t)(fb + 4) * TT + t) * DD);
            const float4* wv  = (const float4*)(winS + fc * XST);
            #pragma unroll
            for (int d4 = 0; d4 < 16; ++d4) {
                float4 w = wv[d4];
                float4 u0 = xr0[d4], u1 = xr1[d4];
                xa0 = fmaf(u0.x, w.x, xa0); xa0 = fmaf(u0.y, w.y, xa0);
                xa0 = fmaf(u0.z, w.z, xa0); xa0 = fmaf(u0.w, w.w, xa0);
                xa1 = fmaf(u1.x, w.x, xa1); xa1 = fmaf(u1.y, w.y, xa1);
                xa1 = fmaf(u1.z, w.z, xa1); xa1 = fmaf(u1.w, w.w, xa1);
            }
        }

        f32x4 acc = {0.f, 0.f, 0.f, 0.f};
        if (t > 0) {
            // two-level signal (r11-proven): ONE sweeper (wg0/wave0) reads the
            // 125 flags, publishes gen; one poller per wg; s_barrier release.
            const unsigned tgt = (unsigned)t;
            if (wave == 0) {
                if (wg == 0) {
                    sweep_all_ge(f1, f2, tgt);
                    if (lane == 0) st_uc_u32(gen, tgt);
                } else if (lane == 0) {
                    poll_ge_pipelined(gen, tgt);
                }
            }
            __builtin_amdgcn_s_barrier();          // release: state_t certified at IC

            // A-operand: 8 contiguous coalesced 512 B region loads -> MFMA frags
            const char* aB = sgB + (size_t)(t & 1) * 32768 + wave * 4096 + aLane;
            uint4 a0 = ld_uc4(aB);
            uint4 a1 = ld_uc4(aB + 512);
            uint4 a2 = ld_uc4(aB + 1024);
            uint4 a3 = ld_uc4(aB + 1536);
            uint4 a4 = ld_uc4(aB + 2048);
            uint4 a5 = ld_uc4(aB + 2560);
            uint4 a6 = ld_uc4(aB + 3072);
            uint4 a7 = ld_uc4(aB + 3584);
            asm volatile("s_waitcnt vmcnt(0)" ::: "memory");
            __builtin_amdgcn_sched_barrier(0);     // rule #18: pin MFMA below wait

            #define MSTEP(mm, areg) { \
                uint4 bu = make_uint4(bw[mm][0], bw[mm][1], bw[mm][2], bw[mm][3]); \
                acc = __builtin_amdgcn_mfma_f32_16x16x32_bf16( \
                    __builtin_bit_cast(bf16x8, areg), \
                    __builtin_bit_cast(bf16x8, bu), acc, 0, 0, 0); }
            MSTEP(0, a0) MSTEP(1, a1) MSTEP(2, a2) MSTEP(3, a3)
            MSTEP(4, a4) MSTEP(5, a5) MSTEP(6, a6) MSTEP(7, a7)
            #undef MSTEP
        }
        if (lane < 32) {
            const int r0 = (lane >> 4) * 4;
            #pragma unroll
            for (int i = 0; i < 4; ++i)
                red[(wave * 8 + r0 + i) * 16 + bcol] = acc[i];
        }
        __syncthreads();

        // finish (wave 1 only): 2 outputs/thread; drain own stores, then ONE
        // plain uncached flag store.
        if (wave == 1) {
            float a0s = xa0, a1s = xa1;
            #pragma unroll
            for (int w = 0; w < 8; ++w) {
                a0s += red[(w * 8 + fb    ) * 16 + fc];
                a1s += red[(w * 8 + fb + 4) * 16 + fc];
            }
            float s0 = fast_tanh(a0s);
            float s1 = fast_tanh(a1s);
            if (t < TT - 1) {
                __bf16 b0 = (__bf16)s0, b1 = (__bf16)s1;
                unsigned short u0, u1;
                __builtin_memcpy(&u0, &b0, 2);
                __builtin_memcpy(&u1, &b1, 2);
                char* dstG = sgB + (size_t)((t + 1) & 1) * 32768;
                st_uc_u16(dstG + pOff0, (unsigned)u0);
                st_uc_u16(dstG + pOff1, (unsigned)u1);
                asm volatile("s_waitcnt vmcnt(0)" ::: "memory");  // state at IC
                if (lane == 0) st_uc_u32(flags + wg, (unsigned)(t + 1));
            }
            float h0 = (fc & 1) ? s0 : s0 * s0;   // even global col -> square
            float h1 = (fc & 1) ? s1 : s1 * s1;
            H[((size_t)t * BB + fb    ) * NN + col0 + fc] = h0;   // off signal path
            H[((size_t)t * BB + fb + 4) * NN + col0 + fc] = h1;
        }
    }
}

// out[b,t,:] = H[t,b,:] @ Wout  (augmentation already applied in H)
__global__ void __launch_bounds__(256, 1)
esn_out(const float* __restrict__ H, const float* __restrict__ Wout,
        float* __restrict__ out)
{
    __shared__ float Hs[64 * 84];
    __shared__ float Ws[80 * 64];
    const int tid = threadIdx.x;
    const int r0  = blockIdx.x * 64;      // global row = t*8 + b
    const int tr  = tid >> 4;             // 0..15
    const int tc  = tid & 15;             // 0..15
    float acc[4][4] = {{0.f}};

    for (int k0 = 0; k0 < NN; k0 += 80) {
        __syncthreads();
        #pragma unroll
        for (int j = 0; j < 5; ++j) {
            int idx = j * 256 + tid;               // 0..1279
            int r = idx / 20, q = idx % 20;
            *(float4*)&Hs[r * 84 + q * 4] =
                *(const float4*)&H[(size_t)(r0 + r) * NN + k0 + q * 4];
        }
        #pragma unroll
        for (int j = 0; j < 5; ++j) {
            int idx = j * 256 + tid;
            int kk = idx >> 4, c4 = idx & 15;
            *(float4*)&Ws[kk * 64 + c4 * 4] =
                *(const float4*)&Wout[(size_t)(k0 + kk) * DD + c4 * 4];
        }
        __syncthreads();
        for (int kk = 0; kk < 80; ++kk) {
            float4 wv = *(const float4*)&Ws[kk * 64 + tc * 4];
            #pragma unroll
            for (int i = 0; i < 4; ++i) {
                float hv = Hs[(tr + 16 * i) * 84 + kk];
                acc[i][0] = fmaf(hv, wv.x, acc[i][0]);
                acc[i][1] = fmaf(hv, wv.y, acc[i][1]);
                acc[i][2] = fmaf(hv, wv.z, acc[i][2]);
                acc[i][3] = fmaf(hv, wv.w, acc[i][3]);
            }
        }
    }
    #pragma unroll
    for (int i = 0; i < 4; ++i) {
        int rg = r0 + tr + 16 * i;
        int t = rg >> 3, b = rg & 7;
        *(float4*)&out[((size_t)b * TT + t) * DD + tc * 4] =
            make_float4(acc[i][0], acc[i][1], acc[i][2], acc[i][3]);
    }
}

extern "C" void kernel_launch(void* const* d_in, const int* in_sizes, int n_in,
                              void* d_out, int out_size, void* d_ws, size_t ws_size,
                              hipStream_t stream)
{
    const float* x    = (const float*)d_in[0];
    const float* Win  = (const float*)d_in[1];
    const float* Wres = (const float*)d_in[2];
    const float* Wout = (const float*)d_in[3];
    float* out = (float*)d_out;

    char* ws = (char*)d_ws;
    unsigned* flags = (unsigned*)ws;                 // 125 dwords
    unsigned* gen   = (unsigned*)(ws + 2048);        // own cache line
    char* sG  = ws + 4096;                           // 2 gens * 32 KB fragment-order state
    float* H  = (float*)(ws + 4096 + 65536);         // 2000*8*2000 f32 = 128 MB

    (void)hipMemsetAsync(d_ws, 0, 4096 + 65536, stream);

    (void)hipFuncSetAttribute((const void*)esn_recur,
                              hipFuncAttributeMaxDynamicSharedMemorySize, LDS_BYTES);
    esn_recur<<<NWG, THREADS, LDS_BYTES, stream>>>(x, Win, Wres, sG, H, flags, gen);
    esn_out<<<250, 256, 0, stream>>>(H, Wout, out);
}